// Round 6
// baseline (105.785 us; speedup 1.0000x reference)
//
#include <hip/hip_runtime.h>

typedef unsigned int   u32;
typedef unsigned short u16;
typedef __bf16 bf16x8 __attribute__((ext_vector_type(8)));
typedef float  f32x4  __attribute__((ext_vector_type(4)));
typedef float  f32x16 __attribute__((ext_vector_type(16)));
typedef _Float16 h16x2 __attribute__((ext_vector_type(2)));

__device__ __forceinline__ u16 f2b(float f) {
  u32 u = __float_as_uint(f);
  u = (u + 0x7fffu + ((u >> 16) & 1u)) >> 16;   // RNE
  return (u16)u;
}
__device__ __forceinline__ float silu_f(float x) { return __fdividef(x, 1.f + __expf(-x)); }

// pack 2 fp32 -> 2 bf16 in one u32 (T12 primitive; no builtin on gfx950)
__device__ __forceinline__ u32 cvt_pk_bf16(float lo, float hi) {
  u32 r;
  asm("v_cvt_pk_bf16_f32 %0, %1, %2" : "=v"(r) : "v"(lo), "v"(hi));
  return r;
}

// fp16 dot: 8 dims per uint4 pair via v_dot2_f32_f16
__device__ __forceinline__ float dot_h8(uint4 q, uint4 k, float acc) {
  acc = __builtin_amdgcn_fdot2(__builtin_bit_cast(h16x2, q.x), __builtin_bit_cast(h16x2, k.x), acc, false);
  acc = __builtin_amdgcn_fdot2(__builtin_bit_cast(h16x2, q.y), __builtin_bit_cast(h16x2, k.y), acc, false);
  acc = __builtin_amdgcn_fdot2(__builtin_bit_cast(h16x2, q.z), __builtin_bit_cast(h16x2, k.z), acc, false);
  acc = __builtin_amdgcn_fdot2(__builtin_bit_cast(h16x2, q.w), __builtin_bit_cast(h16x2, k.w), acc, false);
  return acc;
}

// ---------- prep (merged): blocks 0..63 transpose Wk/Wq; block 64 builds MLP tables ----------
// W0A/W1A: 32x32x16 A-frags (lane l: row=l&31, k-slot=8*(l>>5)+e).
// W1A k-slots permuted by sigma so layer-0 C-output packs directly as layer-1 B-frag.
// BT[t][0..7]=b0[j(e,hf)], [8..15]=b1[j], [16..23]=W2[j]  (j=(e&3)+8*(e>>2)+4*hf), stride 32.
__global__ __launch_bounds__(512) void prep_all(
    const float* __restrict__ Wk, const float* __restrict__ Wq,
    const float* __restrict__ W0, const float* __restrict__ W1,
    const float* __restrict__ b0, const float* __restrict__ b1,
    const float* __restrict__ W2,
    u16* __restrict__ Wkt, u16* __restrict__ Wqt,
    u16* __restrict__ W0A, u16* __restrict__ W1A, float* __restrict__ BT) {
  const int blk = blockIdx.x, t = threadIdx.x;
  if (blk < 64) {
    for (int idx = blk * 512 + t; idx < 65536; idx += 64 * 512) {
      int n = idx >> 8, k = idx & 255;
      Wkt[idx] = f2b(Wk[k * 256 + n]);
      Wqt[idx] = f2b(Wq[k * 256 + n]);
    }
  } else {
    const int h = t >> 6, l = t & 63;
    const int hf = l >> 5, j = l & 31;
    #pragma unroll
    for (int e = 0; e < 8; e++) {
      int k = 8 * hf + e;
      float v0 = (j < 16 && k < 10) ? W0[h * 160 + k * 16 + j] : 0.f;
      W0A[t * 8 + e] = f2b(v0);
      int jin = (k & 3) + 8 * ((k >> 2) & 1) + 4 * (k >> 3);  // sigma(k)
      float v1 = (j < 16) ? W1[h * 256 + jin * 16 + j] : 0.f;
      W1A[t * 8 + e] = f2b(v1);
      int cj = (e & 3) + 8 * (e >> 2) + 4 * hf;
      BT[t * 32 + e]      = b0[h * 16 + cj];
      BT[t * 32 + 8 + e]  = b1[h * 16 + cj];
      BT[t * 32 + 16 + e] = W2[h * 16 + cj];
    }
  }
}

// ---------- GEMM: C_fp16[8192][256] = A_f32[8192][256] @ W + bias ----------
// (verified structure r3/r4; epilogue now emits fp16 for the fdot2 feat path)
#define LDA 72
__global__ __launch_bounds__(256) void gemm_proj(
    const float* __restrict__ A0, const float* __restrict__ A1,
    const u16* __restrict__ B0, const u16* __restrict__ B1,
    const float* __restrict__ bias0, const float* __restrict__ bias1,
    u16* __restrict__ C0, u16* __restrict__ C1) {
  const float* A; const u16* Bt; const float* bias; u16* C;
  if (blockIdx.z == 0) { A = A0; Bt = B0; bias = bias0; C = C0; }
  else                 { A = A1; Bt = B1; bias = bias1; C = C1; }
  __shared__ __align__(16) u16 As[128 * LDA];
  __shared__ __align__(16) u16 Bs[128 * LDA];
  const int t = threadIdx.x;
  const int w = t >> 6, lane = t & 63;
  const int wm = w >> 1, wn = w & 1;
  const int row0 = blockIdx.x * 128, col0 = blockIdx.y * 128;
  f32x4 acc[4][4] = {};
  for (int kk = 0; kk < 256; kk += 64) {
    #pragma unroll
    for (int p = 0; p < 8; p++) {
      int r = p * 16 + (t >> 4), q = (t & 15) * 4;
      float4 v = *(const float4*)(A + (size_t)(row0 + r) * 256 + kk + q);
      uint2 pk;
      pk.x = (u32)f2b(v.x) | ((u32)f2b(v.y) << 16);
      pk.y = (u32)f2b(v.z) | ((u32)f2b(v.w) << 16);
      *(uint2*)(&As[r * LDA + q]) = pk;
    }
    #pragma unroll
    for (int p = 0; p < 4; p++) {
      int r = p * 32 + (t >> 3), q = (t & 7) * 8;
      *(uint4*)(&Bs[r * LDA + q]) = *(const uint4*)(Bt + (size_t)(col0 + r) * 256 + kk + q);
    }
    __syncthreads();
    #pragma unroll
    for (int ks = 0; ks < 2; ks++) {
      bf16x8 af[4], bfr[4];
      #pragma unroll
      for (int i = 0; i < 4; i++) {
        af[i]  = *(const bf16x8*)(&As[(wm * 64 + i * 16 + (lane & 15)) * LDA + ks * 32 + (lane >> 4) * 8]);
        bfr[i] = *(const bf16x8*)(&Bs[(wn * 64 + i * 16 + (lane & 15)) * LDA + ks * 32 + (lane >> 4) * 8]);
      }
      #pragma unroll
      for (int i = 0; i < 4; i++)
        #pragma unroll
        for (int j = 0; j < 4; j++)
          acc[i][j] = __builtin_amdgcn_mfma_f32_16x16x32_bf16(af[i], bfr[j], acc[i][j], 0, 0, 0);
    }
    __syncthreads();
  }
  #pragma unroll
  for (int j = 0; j < 4; j++) {
    int c = col0 + wn * 64 + j * 16 + (lane & 15);
    float bv = bias[c];
    #pragma unroll
    for (int i = 0; i < 4; i++) {
      int r0 = row0 + wm * 64 + i * 16 + (lane >> 4) * 4;
      #pragma unroll
      for (int q = 0; q < 4; q++) {
        _Float16 hv = (_Float16)(acc[i][j][q] + bv);
        C[(size_t)(r0 + q) * 256 + c] = __builtin_bit_cast(u16, hv);
      }
    }
  }
}

// ---------- fused v4: gather+fdot2 (VALU) + MLP (MFMA, cvt_pk packing) ----------
// grid = B*N = 8192; block = 512 = 8 waves; wave = head; lane = (hf, m)
__global__ __launch_bounds__(512) void fused_main(
    const u16* __restrict__ Kh, const u16* __restrict__ Qh,
    const int* __restrict__ nidx, const float* __restrict__ g,
    const u16* __restrict__ W0A, const u16* __restrict__ W1A,
    const float* __restrict__ BT, const float* __restrict__ b2,
    float* __restrict__ out) {
  __shared__ float lout[256];
  const int t = threadIdx.x;
  const int h = t >> 6, lane = t & 63;
  const int hf = lane >> 5, m = lane & 31;
  const int bn = blockIdx.x;
  const int b = bn >> 12;
  const int row = bn * 32 + m;
  const int hs = __builtin_amdgcn_readfirstlane(h);

  // MFMA A-fragments + bias tables
  const bf16x8 a0 = *(const bf16x8*)(W0A + (size_t)(hs * 64 + lane) * 8);
  const bf16x8 a1 = *(const bf16x8*)(W1A + (size_t)(hs * 64 + lane) * 8);
  const float4* btp = (const float4*)(BT + (size_t)t * 32);
  const float4 t0 = btp[0], t1 = btp[1], t2 = btp[2], t3 = btp[3], t4 = btp[4], t5 = btp[5];
  const float bj0[8] = {t0.x, t0.y, t0.z, t0.w, t1.x, t1.y, t1.z, t1.w};
  const float bj1[8] = {t2.x, t2.y, t2.z, t2.w, t3.x, t3.y, t3.z, t3.w};
  const float wj[8]  = {t4.x, t4.y, t4.z, t4.w, t5.x, t5.y, t5.z, t5.w};
  const float b2s = b2[hs];

  // g B-fragment via cvt_pk (lane supplies k-slots 8*hf+e)
  const float* gp = g + (size_t)row * 10;
  u32 pk0, pk1 = 0, pk2 = 0, pk3 = 0;
  {
    float2 v0 = *(const float2*)(gp + hf * 8);
    pk0 = cvt_pk_bf16(v0.x, v0.y);
    if (hf == 0) {
      float2 v1 = *(const float2*)(gp + 2);
      float2 v2 = *(const float2*)(gp + 4);
      float2 v3 = *(const float2*)(gp + 6);
      pk1 = cvt_pk_bf16(v1.x, v1.y);
      pk2 = cvt_pk_bf16(v2.x, v2.y);
      pk3 = cvt_pk_bf16(v3.x, v3.y);
    }
  }
  const bf16x8 gf = __builtin_bit_cast(bf16x8, (uint4){pk0, pk1, pk2, pk3});

  // feat dot (fp16, d = hf*16 .. hf*16+15), two independent chains
  const int kidx = nidx[row];
  const uint4* qp = (const uint4*)(Qh + (size_t)bn * 256 + h * 32 + hf * 16);
  const uint4* kp = (const uint4*)(Kh + ((size_t)b * 4096 + (size_t)kidx) * 256 + h * 32 + hf * 16);
  uint4 q0 = qp[0], q1 = qp[1], k0 = kp[0], k1 = kp[1];
  float dpart = dot_h8(q0, k0, 0.f) + dot_h8(q1, k1, 0.f);

  const f32x16 z = {};

  // layer 0
  f32x16 acc = __builtin_amdgcn_mfma_f32_32x32x16_bf16(a0, gf, z, 0, 0, 0);
  float s0 = silu_f(acc[0] + bj0[0]), s1 = silu_f(acc[1] + bj0[1]);
  float s2 = silu_f(acc[2] + bj0[2]), s3 = silu_f(acc[3] + bj0[3]);
  float s4 = silu_f(acc[4] + bj0[4]), s5 = silu_f(acc[5] + bj0[5]);
  float s6 = silu_f(acc[6] + bj0[6]), s7 = silu_f(acc[7] + bj0[7]);
  uint4 hp = { cvt_pk_bf16(s0, s1), cvt_pk_bf16(s2, s3),
               cvt_pk_bf16(s4, s5), cvt_pk_bf16(s6, s7) };
  const bf16x8 h0b = __builtin_bit_cast(bf16x8, hp);

  // layer 1 + W2 contraction
  acc = __builtin_amdgcn_mfma_f32_32x32x16_bf16(a1, h0b, z, 0, 0, 0);
  float part = 0.f;
  #pragma unroll
  for (int e = 0; e < 8; e++) part += silu_f(acc[e] + bj1[e]) * wj[e];

  // cross-half combine + final
  float osum = part + __shfl_xor(part, 32, 64);
  float feat = (dpart + __shfl_xor(dpart, 32, 64)) * 0.17677669529663687f;
  float res = feat + silu_f(osum + b2s);

  if (hf == 0) lout[m * 8 + h] = res;
  __syncthreads();
  if (t < 64) {
    float4 v = ((const float4*)lout)[t];
    ((float4*)(out + (size_t)bn * 256))[t] = v;
  }
}

extern "C" void kernel_launch(void* const* d_in, const int* in_sizes, int n_in,
                              void* d_out, int out_size, void* d_ws, size_t ws_size,
                              hipStream_t stream) {
  const float* g_in = (const float*)d_in[0];
  // d_in[1] = nbhd_mask: unused by the reference
  const float* kf   = (const float*)d_in[2];
  const float* qf   = (const float*)d_in[3];
  const int*   idx  = (const int*)d_in[4];
  const float* Wk   = (const float*)d_in[5];
  const float* bk   = (const float*)d_in[6];
  const float* Wq   = (const float*)d_in[7];
  const float* bq   = (const float*)d_in[8];
  const float* W0   = (const float*)d_in[9];
  const float* b0   = (const float*)d_in[10];
  const float* W1   = (const float*)d_in[11];
  const float* b1   = (const float*)d_in[12];
  const float* W2   = (const float*)d_in[13];
  const float* b2   = (const float*)d_in[14];

  char* ws = (char*)d_ws;
  u16*   Kh  = (u16*)ws;                                        // 4 MB
  u16*   Qh  = (u16*)(ws + 4u * 1024 * 1024);                   // 4 MB
  u16*   Wkt = (u16*)(ws + 8u * 1024 * 1024);                   // 128 KB
  u16*   Wqt = (u16*)(ws + 8u * 1024 * 1024 + 131072);          // 128 KB
  u16*   W0A = (u16*)(ws + 8u * 1024 * 1024 + 262144);          // 8 KB
  u16*   W1A = (u16*)(ws + 8u * 1024 * 1024 + 262144 + 8192);   // 8 KB
  float* BT  = (float*)(ws + 8u * 1024 * 1024 + 262144 + 16384);// 64 KB

  prep_all<<<65, 512, 0, stream>>>(Wk, Wq, W0, W1, b0, b1, W2, Wkt, Wqt, W0A, W1A, BT);
  gemm_proj<<<dim3(64, 2, 2), 256, 0, stream>>>(kf, qf, Wkt, Wqt, bk, bq, Kh, Qh);
  fused_main<<<8192, 512, 0, stream>>>(Kh, Qh, idx, g_in, W0A, W1A, BT, b2,
                                       (float*)d_out);
}

// Round 7
// 105.421 us; speedup vs baseline: 1.0035x; 1.0035x over previous
//
#include <hip/hip_runtime.h>
#include <hip/hip_fp16.h>

typedef unsigned int   u32;
typedef unsigned short u16;
typedef __bf16 bf16x8 __attribute__((ext_vector_type(8)));
typedef float  f32x4  __attribute__((ext_vector_type(4)));
typedef float  f32x16 __attribute__((ext_vector_type(16)));

__device__ __forceinline__ u16 f2b(float f) {
  u32 u = __float_as_uint(f);
  u = (u + 0x7fffu + ((u >> 16) & 1u)) >> 16;   // RNE
  return (u16)u;
}
__device__ __forceinline__ float silu_f(float x) { return __fdividef(x, 1.f + __expf(-x)); }

// 8 fp16 dims per uint4 pair via v_pk_fma_f16 (no inline asm, no exotic builtins)
__device__ __forceinline__ __half2 fma8(uint4 q, uint4 k, __half2 acc) {
  const __half2* qh = (const __half2*)&q;
  const __half2* kh = (const __half2*)&k;
  #pragma unroll
  for (int i = 0; i < 4; i++) acc = __hfma2(qh[i], kh[i], acc);
  return acc;
}

// ---------- prep (merged): blocks 0..63 transpose Wk/Wq; block 64 builds MLP tables ----------
// W0A/W1A: 32x32x16 A-frags (lane l: row=l&31, k-slot=8*(l>>5)+e).
// W1A k-slots permuted by sigma so layer-0 C-output packs directly as layer-1 B-frag.
// BT[t][0..7]=b0[j(e,hf)], [8..15]=b1[j], [16..23]=W2[j]  (j=(e&3)+8*(e>>2)+4*hf), stride 32.
__global__ __launch_bounds__(512) void prep_all(
    const float* __restrict__ Wk, const float* __restrict__ Wq,
    const float* __restrict__ W0, const float* __restrict__ W1,
    const float* __restrict__ b0, const float* __restrict__ b1,
    const float* __restrict__ W2,
    u16* __restrict__ Wkt, u16* __restrict__ Wqt,
    u16* __restrict__ W0A, u16* __restrict__ W1A, float* __restrict__ BT) {
  const int blk = blockIdx.x, t = threadIdx.x;
  if (blk < 64) {
    for (int idx = blk * 512 + t; idx < 65536; idx += 64 * 512) {
      int n = idx >> 8, k = idx & 255;
      Wkt[idx] = f2b(Wk[k * 256 + n]);
      Wqt[idx] = f2b(Wq[k * 256 + n]);
    }
  } else {
    const int h = t >> 6, l = t & 63;
    const int hf = l >> 5, j = l & 31;
    #pragma unroll
    for (int e = 0; e < 8; e++) {
      int k = 8 * hf + e;
      float v0 = (j < 16 && k < 10) ? W0[h * 160 + k * 16 + j] : 0.f;
      W0A[t * 8 + e] = f2b(v0);
      int jin = (k & 3) + 8 * ((k >> 2) & 1) + 4 * (k >> 3);  // sigma(k)
      float v1 = (j < 16) ? W1[h * 256 + jin * 16 + j] : 0.f;
      W1A[t * 8 + e] = f2b(v1);
      int cj = (e & 3) + 8 * (e >> 2) + 4 * hf;
      BT[t * 32 + e]      = b0[h * 16 + cj];
      BT[t * 32 + 8 + e]  = b1[h * 16 + cj];
      BT[t * 32 + 16 + e] = W2[h * 16 + cj];
    }
  }
}

// ---------- GEMM: C_fp16[8192][256] = A_f32[8192][256] @ W + bias ----------
#define LDA 72
__global__ __launch_bounds__(256) void gemm_proj(
    const float* __restrict__ A0, const float* __restrict__ A1,
    const u16* __restrict__ B0, const u16* __restrict__ B1,
    const float* __restrict__ bias0, const float* __restrict__ bias1,
    u16* __restrict__ C0, u16* __restrict__ C1) {
  const float* A; const u16* Bt; const float* bias; u16* C;
  if (blockIdx.z == 0) { A = A0; Bt = B0; bias = bias0; C = C0; }
  else                 { A = A1; Bt = B1; bias = bias1; C = C1; }
  __shared__ __align__(16) u16 As[128 * LDA];
  __shared__ __align__(16) u16 Bs[128 * LDA];
  const int t = threadIdx.x;
  const int w = t >> 6, lane = t & 63;
  const int wm = w >> 1, wn = w & 1;
  const int row0 = blockIdx.x * 128, col0 = blockIdx.y * 128;
  f32x4 acc[4][4] = {};
  for (int kk = 0; kk < 256; kk += 64) {
    #pragma unroll
    for (int p = 0; p < 8; p++) {
      int r = p * 16 + (t >> 4), q = (t & 15) * 4;
      float4 v = *(const float4*)(A + (size_t)(row0 + r) * 256 + kk + q);
      uint2 pk;
      pk.x = (u32)f2b(v.x) | ((u32)f2b(v.y) << 16);
      pk.y = (u32)f2b(v.z) | ((u32)f2b(v.w) << 16);
      *(uint2*)(&As[r * LDA + q]) = pk;
    }
    #pragma unroll
    for (int p = 0; p < 4; p++) {
      int r = p * 32 + (t >> 3), q = (t & 7) * 8;
      *(uint4*)(&Bs[r * LDA + q]) = *(const uint4*)(Bt + (size_t)(col0 + r) * 256 + kk + q);
    }
    __syncthreads();
    #pragma unroll
    for (int ks = 0; ks < 2; ks++) {
      bf16x8 af[4], bfr[4];
      #pragma unroll
      for (int i = 0; i < 4; i++) {
        af[i]  = *(const bf16x8*)(&As[(wm * 64 + i * 16 + (lane & 15)) * LDA + ks * 32 + (lane >> 4) * 8]);
        bfr[i] = *(const bf16x8*)(&Bs[(wn * 64 + i * 16 + (lane & 15)) * LDA + ks * 32 + (lane >> 4) * 8]);
      }
      #pragma unroll
      for (int i = 0; i < 4; i++)
        #pragma unroll
        for (int j = 0; j < 4; j++)
          acc[i][j] = __builtin_amdgcn_mfma_f32_16x16x32_bf16(af[i], bfr[j], acc[i][j], 0, 0, 0);
    }
    __syncthreads();
  }
  #pragma unroll
  for (int j = 0; j < 4; j++) {
    int c = col0 + wn * 64 + j * 16 + (lane & 15);
    float bv = bias[c];
    #pragma unroll
    for (int i = 0; i < 4; i++) {
      int r0 = row0 + wm * 64 + i * 16 + (lane >> 4) * 4;
      #pragma unroll
      for (int q = 0; q < 4; q++) {
        _Float16 hv = (_Float16)(acc[i][j][q] + bv);
        C[(size_t)(r0 + q) * 256 + c] = __builtin_bit_cast(u16, hv);
      }
    }
  }
}

// ---------- fused v5: gather+pk_fma dot (VALU) + MLP (MFMA, bias-as-C) ----------
// grid = B*N = 8192; block = 512 = 8 waves; wave = head; lane = (hf, m)
__global__ __launch_bounds__(512) void fused_main(
    const u16* __restrict__ Kh, const u16* __restrict__ Qh,
    const int* __restrict__ nidx, const float* __restrict__ g,
    const u16* __restrict__ W0A, const u16* __restrict__ W1A,
    const float* __restrict__ BT, const float* __restrict__ b2,
    float* __restrict__ out) {
  __shared__ float lout[256];
  const int t = threadIdx.x;
  const int h = t >> 6, lane = t & 63;
  const int hf = lane >> 5, m = lane & 31;
  const int bn = blockIdx.x;
  const int b = bn >> 12;
  const u32 row = (u32)bn * 32 + m;
  const int hs = __builtin_amdgcn_readfirstlane(h);

  // MFMA A-fragments + per-lane bias tables
  const bf16x8 a0 = *(const bf16x8*)(W0A + ((u32)(hs * 64 + lane) << 3));
  const bf16x8 a1 = *(const bf16x8*)(W1A + ((u32)(hs * 64 + lane) << 3));
  const float4* btp = (const float4*)(BT + ((u32)t << 5));
  const float4 t0 = btp[0], t1 = btp[1], t2 = btp[2], t3 = btp[3], t4 = btp[4], t5 = btp[5];
  const float wj[8]  = {t4.x, t4.y, t4.z, t4.w, t5.x, t5.y, t5.z, t5.w};
  const float b2s = b2[hs];

  // bias-as-C operands (upper 8 elems correspond to zeroed A rows -> unused)
  f32x16 c0 = {};
  c0[0] = t0.x; c0[1] = t0.y; c0[2] = t0.z; c0[3] = t0.w;
  c0[4] = t1.x; c0[5] = t1.y; c0[6] = t1.z; c0[7] = t1.w;
  f32x16 c1 = {};
  c1[0] = t2.x; c1[1] = t2.y; c1[2] = t2.z; c1[3] = t2.w;
  c1[4] = t3.x; c1[5] = t3.y; c1[6] = t3.z; c1[7] = t3.w;

  // g B-fragment (lane supplies k-slots 8*hf+e); plain casts -> compiler packs
  const float* gp = g + row * 10u;
  bf16x8 gf = {};
  {
    float2 v0 = *(const float2*)(gp + hf * 8);
    gf[0] = (__bf16)v0.x; gf[1] = (__bf16)v0.y;
    if (hf == 0) {
      float2 v1 = *(const float2*)(gp + 2);
      float2 v2 = *(const float2*)(gp + 4);
      float2 v3 = *(const float2*)(gp + 6);
      gf[2] = (__bf16)v1.x; gf[3] = (__bf16)v1.y;
      gf[4] = (__bf16)v2.x; gf[5] = (__bf16)v2.y;
      gf[6] = (__bf16)v3.x; gf[7] = (__bf16)v3.y;
    }
  }

  // feat dot (fp16 packed fma, d = hf*16 .. hf*16+15)
  const u32 kidx = (u32)nidx[row];
  const uint4* qp = (const uint4*)(Qh + ((u32)bn << 8) + (h << 5) + (hf << 4));
  const uint4* kp = (const uint4*)(Kh + (((u32)b << 20) + (kidx << 8)) + (h << 5) + (hf << 4));
  uint4 q0 = qp[0], q1 = qp[1], k0 = kp[0], k1 = kp[1];
  __half2 dacc = __floats2half2_rn(0.f, 0.f);
  dacc = fma8(q0, k0, dacc);
  dacc = fma8(q1, k1, dacc);
  float dpart = __low2float(dacc) + __high2float(dacc);

  // layer 0 (bias via C operand)
  f32x16 acc = __builtin_amdgcn_mfma_f32_32x32x16_bf16(a0, gf, c0, 0, 0, 0);
  bf16x8 h0b;
  #pragma unroll
  for (int e = 0; e < 8; e++) h0b[e] = (__bf16)silu_f(acc[e]);

  // layer 1 + W2 contraction
  acc = __builtin_amdgcn_mfma_f32_32x32x16_bf16(a1, h0b, c1, 0, 0, 0);
  float part = 0.f;
  #pragma unroll
  for (int e = 0; e < 8; e++) part += silu_f(acc[e]) * wj[e];

  // cross-half combine + final
  float osum = part + __shfl_xor(part, 32, 64);
  float feat = (dpart + __shfl_xor(dpart, 32, 64)) * 0.17677669529663687f;
  float res = feat + silu_f(osum + b2s);

  if (hf == 0) lout[m * 8 + h] = res;
  __syncthreads();
  if (t < 64) {
    float4 v = ((const float4*)lout)[t];
    ((float4*)(out + ((size_t)bn << 8)))[t] = v;
  }
}

extern "C" void kernel_launch(void* const* d_in, const int* in_sizes, int n_in,
                              void* d_out, int out_size, void* d_ws, size_t ws_size,
                              hipStream_t stream) {
  const float* g_in = (const float*)d_in[0];
  // d_in[1] = nbhd_mask: unused by the reference
  const float* kf   = (const float*)d_in[2];
  const float* qf   = (const float*)d_in[3];
  const int*   idx  = (const int*)d_in[4];
  const float* Wk   = (const float*)d_in[5];
  const float* bk   = (const float*)d_in[6];
  const float* Wq   = (const float*)d_in[7];
  const float* bq   = (const float*)d_in[8];
  const float* W0   = (const float*)d_in[9];
  const float* b0   = (const float*)d_in[10];
  const float* W1   = (const float*)d_in[11];
  const float* b1   = (const float*)d_in[12];
  const float* W2   = (const float*)d_in[13];
  const float* b2   = (const float*)d_in[14];

  char* ws = (char*)d_ws;
  u16*   Kh  = (u16*)ws;                                        // 4 MB
  u16*   Qh  = (u16*)(ws + 4u * 1024 * 1024);                   // 4 MB
  u16*   Wkt = (u16*)(ws + 8u * 1024 * 1024);                   // 128 KB
  u16*   Wqt = (u16*)(ws + 8u * 1024 * 1024 + 131072);          // 128 KB
  u16*   W0A = (u16*)(ws + 8u * 1024 * 1024 + 262144);          // 8 KB
  u16*   W1A = (u16*)(ws + 8u * 1024 * 1024 + 262144 + 8192);   // 8 KB
  float* BT  = (float*)(ws + 8u * 1024 * 1024 + 262144 + 16384);// 64 KB

  prep_all<<<65, 512, 0, stream>>>(Wk, Wq, W0, W1, b0, b1, W2, Wkt, Wqt, W0A, W1A, BT);
  gemm_proj<<<dim3(64, 2, 2), 256, 0, stream>>>(kf, qf, Wkt, Wqt, bk, bq, Kh, Qh);
  fused_main<<<8192, 512, 0, stream>>>(Kh, Qh, idx, g_in, W0A, W1A, BT, b2,
                                       (float*)d_out);
}

// Round 8
// 104.969 us; speedup vs baseline: 1.0078x; 1.0043x over previous
//
#include <hip/hip_runtime.h>

typedef unsigned int   u32;
typedef unsigned short u16;
typedef __bf16 bf16x8 __attribute__((ext_vector_type(8)));
typedef float  f32x4  __attribute__((ext_vector_type(4)));
typedef float  f32x16 __attribute__((ext_vector_type(16)));

__device__ __forceinline__ u16 f2b(float f) {
  u32 u = __float_as_uint(f);
  u = (u + 0x7fffu + ((u >> 16) & 1u)) >> 16;   // RNE
  return (u16)u;
}
__device__ __forceinline__ float b2f_lo(u32 u) { return __uint_as_float(u << 16); }
__device__ __forceinline__ float b2f_hi(u32 u) { return __uint_as_float(u & 0xffff0000u); }
__device__ __forceinline__ float silu_f(float x) { return __fdividef(x, 1.f + __expf(-x)); }

__device__ __forceinline__ float dot8(uint4 q, uint4 k, float acc) {
  acc += b2f_lo(q.x) * b2f_lo(k.x) + b2f_hi(q.x) * b2f_hi(k.x);
  acc += b2f_lo(q.y) * b2f_lo(k.y) + b2f_hi(q.y) * b2f_hi(k.y);
  acc += b2f_lo(q.z) * b2f_lo(k.z) + b2f_hi(q.z) * b2f_hi(k.z);
  acc += b2f_lo(q.w) * b2f_lo(k.w) + b2f_hi(q.w) * b2f_hi(k.w);
  return acc;
}

// ---------- prep (merged): blocks 0..63 transpose Wk/Wq; block 64 builds MLP tables ----------
// W0A/W1A: 32x32x16 A-frags (lane l: row=l&31, k-slot=8*(l>>5)+e).
// W1A k-slots permuted by sigma so layer-0 C-output packs directly as layer-1 B-frag.
// BT[t][0..7]=b0[j(e,hf)], [8..15]=b1[j], [16..23]=W2[j]  (j=(e&3)+8*(e>>2)+4*hf), stride 32.
__global__ __launch_bounds__(512) void prep_all(
    const float* __restrict__ Wk, const float* __restrict__ Wq,
    const float* __restrict__ W0, const float* __restrict__ W1,
    const float* __restrict__ b0, const float* __restrict__ b1,
    const float* __restrict__ W2,
    u16* __restrict__ Wkt, u16* __restrict__ Wqt,
    u16* __restrict__ W0A, u16* __restrict__ W1A, float* __restrict__ BT) {
  const int blk = blockIdx.x, t = threadIdx.x;
  if (blk < 64) {
    for (int idx = blk * 512 + t; idx < 65536; idx += 64 * 512) {
      int n = idx >> 8, k = idx & 255;
      Wkt[idx] = f2b(Wk[k * 256 + n]);
      Wqt[idx] = f2b(Wq[k * 256 + n]);
    }
  } else {
    const int h = t >> 6, l = t & 63;
    const int hf = l >> 5, j = l & 31;
    #pragma unroll
    for (int e = 0; e < 8; e++) {
      int k = 8 * hf + e;
      float v0 = (j < 16 && k < 10) ? W0[h * 160 + k * 16 + j] : 0.f;
      W0A[t * 8 + e] = f2b(v0);
      int jin = (k & 3) + 8 * ((k >> 2) & 1) + 4 * (k >> 3);  // sigma(k)
      float v1 = (j < 16) ? W1[h * 256 + jin * 16 + j] : 0.f;
      W1A[t * 8 + e] = f2b(v1);
      int cj = (e & 3) + 8 * (e >> 2) + 4 * hf;
      BT[t * 32 + e]      = b0[h * 16 + cj];
      BT[t * 32 + 8 + e]  = b1[h * 16 + cj];
      BT[t * 32 + 16 + e] = W2[h * 16 + cj];
    }
  }
}

// ---------- GEMM: C_bf16[8192][256] = A_f32[8192][256] @ W + bias (verified r3/r4) ----------
#define LDA 72
__global__ __launch_bounds__(256) void gemm_proj(
    const float* __restrict__ A0, const float* __restrict__ A1,
    const u16* __restrict__ B0, const u16* __restrict__ B1,
    const float* __restrict__ bias0, const float* __restrict__ bias1,
    u16* __restrict__ C0, u16* __restrict__ C1) {
  const float* A; const u16* Bt; const float* bias; u16* C;
  if (blockIdx.z == 0) { A = A0; Bt = B0; bias = bias0; C = C0; }
  else                 { A = A1; Bt = B1; bias = bias1; C = C1; }
  __shared__ __align__(16) u16 As[128 * LDA];
  __shared__ __align__(16) u16 Bs[128 * LDA];
  const int t = threadIdx.x;
  const int w = t >> 6, lane = t & 63;
  const int wm = w >> 1, wn = w & 1;
  const int row0 = blockIdx.x * 128, col0 = blockIdx.y * 128;
  f32x4 acc[4][4] = {};
  for (int kk = 0; kk < 256; kk += 64) {
    #pragma unroll
    for (int p = 0; p < 8; p++) {
      int r = p * 16 + (t >> 4), q = (t & 15) * 4;
      float4 v = *(const float4*)(A + (size_t)(row0 + r) * 256 + kk + q);
      uint2 pk;
      pk.x = (u32)f2b(v.x) | ((u32)f2b(v.y) << 16);
      pk.y = (u32)f2b(v.z) | ((u32)f2b(v.w) << 16);
      *(uint2*)(&As[r * LDA + q]) = pk;
    }
    #pragma unroll
    for (int p = 0; p < 4; p++) {
      int r = p * 32 + (t >> 3), q = (t & 7) * 8;
      *(uint4*)(&Bs[r * LDA + q]) = *(const uint4*)(Bt + (size_t)(col0 + r) * 256 + kk + q);
    }
    __syncthreads();
    #pragma unroll
    for (int ks = 0; ks < 2; ks++) {
      bf16x8 af[4], bfr[4];
      #pragma unroll
      for (int i = 0; i < 4; i++) {
        af[i]  = *(const bf16x8*)(&As[(wm * 64 + i * 16 + (lane & 15)) * LDA + ks * 32 + (lane >> 4) * 8]);
        bfr[i] = *(const bf16x8*)(&Bs[(wn * 64 + i * 16 + (lane & 15)) * LDA + ks * 32 + (lane >> 4) * 8]);
      }
      #pragma unroll
      for (int i = 0; i < 4; i++)
        #pragma unroll
        for (int j = 0; j < 4; j++)
          acc[i][j] = __builtin_amdgcn_mfma_f32_16x16x32_bf16(af[i], bfr[j], acc[i][j], 0, 0, 0);
    }
    __syncthreads();
  }
  #pragma unroll
  for (int j = 0; j < 4; j++) {
    int c = col0 + wn * 64 + j * 16 + (lane & 15);
    float bv = bias[c];
    #pragma unroll
    for (int i = 0; i < 4; i++) {
      int r0 = row0 + wm * 64 + i * 16 + (lane >> 4) * 4;
      #pragma unroll
      for (int q = 0; q < 4; q++)
        C[(size_t)(r0 + q) * 256 + c] = f2b(acc[i][j][q] + bv);
    }
  }
}

// ---------- fused v6: r4 arithmetic, decoupled execution ----------
// grid = (B*N, 2) ; block = 256 = 4 waves; wave = head (hg*4 + t>>6); lane = (hf, m)
// No LDS, no __syncthreads, direct scattered stores -> waves retire independently.
__global__ __launch_bounds__(256) void fused_main(
    const u16* __restrict__ Kbf, const u16* __restrict__ Qbf,
    const int* __restrict__ nidx, const float* __restrict__ g,
    const u16* __restrict__ W0A, const u16* __restrict__ W1A,
    const float* __restrict__ BT, const float* __restrict__ b2,
    float* __restrict__ out) {
  const int t = threadIdx.x;
  const int lane = t & 63;
  const int hf = lane >> 5, m = lane & 31;
  const int bn = blockIdx.x;
  const int b = bn >> 12;
  const u32 row = (u32)bn * 32 + m;
  const int hs = __builtin_amdgcn_readfirstlane(blockIdx.y * 4 + (t >> 6));

  // MFMA A-fragments + per-lane bias tables (indexed by (hs, lane))
  const bf16x8 a0 = *(const bf16x8*)(W0A + ((u32)(hs * 64 + lane) << 3));
  const bf16x8 a1 = *(const bf16x8*)(W1A + ((u32)(hs * 64 + lane) << 3));
  const float4* btp = (const float4*)(BT + ((u32)(hs * 64 + lane) << 5));
  const float4 t0 = btp[0], t1 = btp[1], t2 = btp[2], t3 = btp[3], t4 = btp[4], t5 = btp[5];
  const float bj0[8] = {t0.x, t0.y, t0.z, t0.w, t1.x, t1.y, t1.z, t1.w};
  const float bj1[8] = {t2.x, t2.y, t2.z, t2.w, t3.x, t3.y, t3.z, t3.w};
  const float wj[8]  = {t4.x, t4.y, t4.z, t4.w, t5.x, t5.y, t5.z, t5.w};
  const float b2s = b2[hs];

  // g B-fragment (lane supplies k-slots 8*hf+e)
  const float* gp = g + (size_t)row * 10;
  bf16x8 gf = {};
  {
    float2 v0 = *(const float2*)(gp + hf * 8);
    gf[0] = (__bf16)v0.x; gf[1] = (__bf16)v0.y;
    if (hf == 0) {
      float2 v1 = *(const float2*)(gp + 2);
      float2 v2 = *(const float2*)(gp + 4);
      float2 v3 = *(const float2*)(gp + 6);
      gf[2] = (__bf16)v1.x; gf[3] = (__bf16)v1.y;
      gf[4] = (__bf16)v2.x; gf[5] = (__bf16)v2.y;
      gf[6] = (__bf16)v3.x; gf[7] = (__bf16)v3.y;
    }
  }

  // feat dot (bf16 unpack + fp32 fma, d = hf*16 .. hf*16+15)
  const int kidx = nidx[row];
  const uint4* qp = (const uint4*)(Qbf + (size_t)bn * 256 + hs * 32 + hf * 16);
  const uint4* kp = (const uint4*)(Kbf + ((size_t)b * 4096 + (size_t)kidx) * 256 + hs * 32 + hf * 16);
  uint4 q0 = qp[0], q1 = qp[1], k0 = kp[0], k1 = kp[1];
  float dpart = dot8(q1, k1, dot8(q0, k0, 0.f));

  const f32x16 z = {};

  // layer 0
  f32x16 acc = __builtin_amdgcn_mfma_f32_32x32x16_bf16(a0, gf, z, 0, 0, 0);
  bf16x8 h0b;
  #pragma unroll
  for (int e = 0; e < 8; e++) h0b[e] = (__bf16)silu_f(acc[e] + bj0[e]);

  // layer 1 + W2 contraction
  acc = __builtin_amdgcn_mfma_f32_32x32x16_bf16(a1, h0b, z, 0, 0, 0);
  float part = 0.f;
  #pragma unroll
  for (int e = 0; e < 8; e++) part += silu_f(acc[e] + bj1[e]) * wj[e];

  // cross-half combine + final
  float osum = part + __shfl_xor(part, 32, 64);
  float feat = (dpart + __shfl_xor(dpart, 32, 64)) * 0.17677669529663687f;
  float res = feat + silu_f(osum + b2s);

  // direct store: out[(b,n,m), h] ; hf==0 lanes cover all 32 m
  if (hf == 0) out[((size_t)bn << 8) + m * 8 + hs] = res;
}

extern "C" void kernel_launch(void* const* d_in, const int* in_sizes, int n_in,
                              void* d_out, int out_size, void* d_ws, size_t ws_size,
                              hipStream_t stream) {
  const float* g_in = (const float*)d_in[0];
  // d_in[1] = nbhd_mask: unused by the reference
  const float* kf   = (const float*)d_in[2];
  const float* qf   = (const float*)d_in[3];
  const int*   idx  = (const int*)d_in[4];
  const float* Wk   = (const float*)d_in[5];
  const float* bk   = (const float*)d_in[6];
  const float* Wq   = (const float*)d_in[7];
  const float* bq   = (const float*)d_in[8];
  const float* W0   = (const float*)d_in[9];
  const float* b0   = (const float*)d_in[10];
  const float* W1   = (const float*)d_in[11];
  const float* b1   = (const float*)d_in[12];
  const float* W2   = (const float*)d_in[13];
  const float* b2   = (const float*)d_in[14];

  char* ws = (char*)d_ws;
  u16*   Kbf = (u16*)ws;                                        // 4 MB
  u16*   Qbf = (u16*)(ws + 4u * 1024 * 1024);                   // 4 MB
  u16*   Wkt = (u16*)(ws + 8u * 1024 * 1024);                   // 128 KB
  u16*   Wqt = (u16*)(ws + 8u * 1024 * 1024 + 131072);          // 128 KB
  u16*   W0A = (u16*)(ws + 8u * 1024 * 1024 + 262144);          // 8 KB
  u16*   W1A = (u16*)(ws + 8u * 1024 * 1024 + 262144 + 8192);   // 8 KB
  float* BT  = (float*)(ws + 8u * 1024 * 1024 + 262144 + 16384);// 64 KB

  prep_all<<<65, 512, 0, stream>>>(Wk, Wq, W0, W1, b0, b1, W2, Wkt, Wqt, W0A, W1A, BT);
  gemm_proj<<<dim3(64, 2, 2), 256, 0, stream>>>(kf, qf, Wkt, Wqt, bk, bq, Kbf, Qbf);
  fused_main<<<dim3(8192, 2), 256, 0, stream>>>(Kbf, Qbf, idx, g_in, W0A, W1A, BT, b2,
                                                (float*)d_out);
}